// Round 7
// baseline (79.764 us; speedup 1.0000x reference)
//
#include <hip/hip_runtime.h>
#include <hip/hip_bf16.h>

typedef float f32x4 __attribute__((ext_vector_type(4)));
typedef __bf16 bf16x8 __attribute__((ext_vector_type(8)));
typedef unsigned short u16x8 __attribute__((ext_vector_type(8)));

#define N_NODES 10000
#define DIM 512
#define MPAD 10112   // 158 * 64
#define DEGCAP 96    // max degree bucket (Poisson(15): P(deg>=96) ~ 1e-40)

// ---------------- zero cnt ------------------------------------------------------
__global__ __launch_bounds__(256) void zero_kernel(int* __restrict__ cnt) {
    cnt[blockIdx.x * 256 + threadIdx.x] = 0;
}

// ====== phase1: packw | layernorm | bucket-fill adjacency (grid-partitioned) ===
__global__ __launch_bounds__(256) void phase1_kernel(
    const float* __restrict__ wl, const float* __restrict__ wr,
    __hip_bfloat16* __restrict__ W,
    const float* __restrict__ xin, const float* __restrict__ gamma,
    const float* __restrict__ beta, __hip_bfloat16* __restrict__ A,
    const int* __restrict__ eidx, int* __restrict__ cnt, int* __restrict__ adj,
    int E, int fill_start) {
    int b = blockIdx.x;
    int tid = threadIdx.x;

    if (b < 512) {
        // pack W = [w_l | w_r] rows -> bf16 [512][1024]
        int idx = b * 256 + tid;
        int base = idx * 4;
        int d = base >> 10;
        int k = base & 1023;
        const float* src = (k < 512) ? (wl + d * 512 + k) : (wr + d * 512 + (k - 512));
        float4 v = *(const float4*)src;
        __hip_bfloat16* o = W + (size_t)d * 1024 + k;
        o[0] = __float2bfloat16(v.x);
        o[1] = __float2bfloat16(v.y);
        o[2] = __float2bfloat16(v.z);
        o[3] = __float2bfloat16(v.w);
    } else if (b < fill_start) {
        // LayerNorm, one wave per row
        int row = (b - 512) * 4 + (tid >> 6);
        int lane = tid & 63;
        const float* xr = xin + (size_t)row * DIM + lane * 8;
        float4 v0 = *(const float4*)xr;
        float4 v1 = *(const float4*)(xr + 4);
        float s  = v0.x + v0.y + v0.z + v0.w + v1.x + v1.y + v1.z + v1.w;
        float ss = v0.x*v0.x + v0.y*v0.y + v0.z*v0.z + v0.w*v0.w
                 + v1.x*v1.x + v1.y*v1.y + v1.z*v1.z + v1.w*v1.w;
        #pragma unroll
        for (int o = 32; o > 0; o >>= 1) {
            s  += __shfl_xor(s, o, 64);
            ss += __shfl_xor(ss, o, 64);
        }
        float mu  = s * (1.0f / 512.0f);
        float var = ss * (1.0f / 512.0f) - mu * mu;
        float rstd = rsqrtf(var + 1e-5f);
        float4 g0 = *(const float4*)(gamma + lane * 8);
        float4 g1 = *(const float4*)(gamma + lane * 8 + 4);
        float4 b0 = *(const float4*)(beta + lane * 8);
        float4 b1 = *(const float4*)(beta + lane * 8 + 4);
        __hip_bfloat16* a = A + (size_t)row * 1024 + 512 + lane * 8;
        a[0] = __float2bfloat16((v0.x - mu) * rstd * g0.x + b0.x);
        a[1] = __float2bfloat16((v0.y - mu) * rstd * g0.y + b0.y);
        a[2] = __float2bfloat16((v0.z - mu) * rstd * g0.z + b0.z);
        a[3] = __float2bfloat16((v0.w - mu) * rstd * g0.w + b0.w);
        a[4] = __float2bfloat16((v1.x - mu) * rstd * g1.x + b1.x);
        a[5] = __float2bfloat16((v1.y - mu) * rstd * g1.y + b1.y);
        a[6] = __float2bfloat16((v1.z - mu) * rstd * g1.z + b1.z);
        a[7] = __float2bfloat16((v1.w - mu) * rstd * g1.w + b1.w);
    } else {
        // single-pass bucket fill: adj[dst*DEGCAP + pos] = src
        int i = (b - fill_start) * 256 + tid;
        if (i < E) {
            int dst = eidx[E + i];
            int src = eidx[i];
            int pos = atomicAdd(&cnt[dst], 1);
            if (pos < DEGCAP) adj[dst * DEGCAP + pos] = src;
        }
    }
}

// ---------------- gather: XCD-affine dim-quarters, wave per (node, quarter) ----
// blockIdx%8 -> XCD (round-robin heuristic); quarter = (blockIdx%8)&3 so each
// XCD touches only x[:, q*128:(q+1)*128] = 2.5 MB -> L2-resident.
__global__ __launch_bounds__(256) void gather_kernel(const int* __restrict__ cnt,
                                                     const int* __restrict__ adj,
                                                     __hip_bfloat16* __restrict__ A) {
    int b = blockIdx.x;                 // 0..9999
    int x = b & 7;                      // nominal XCD
    int t = b >> 3;                     // 0..1249
    int q = x & 3;                      // dim quarter
    int half = x >> 2;                  // 0 or 1
    int node = ((half * 1250 + t) << 2) + (threadIdx.x >> 6);
    int lane = threadIdx.x & 63;
    int deg = cnt[node];
    const int* al = adj + node * DEGCAP;
    // x chunk: dims [q*128, q*128+128) of the LN half -> byte offset
    const char* Abase = (const char*)A;
    size_t coff = 1024 + (size_t)q * 256 + lane * 4;   // bytes within row (x half)
    float a0 = 0.f, a1 = 0.f;
    int j = 0;
    for (; j + 4 <= deg; j += 4) {
        int n0 = al[j], n1 = al[j + 1], n2 = al[j + 2], n3 = al[j + 3];
        unsigned v0 = *(const unsigned*)(Abase + (size_t)n0 * 2048 + coff);
        unsigned v1 = *(const unsigned*)(Abase + (size_t)n1 * 2048 + coff);
        unsigned v2 = *(const unsigned*)(Abase + (size_t)n2 * 2048 + coff);
        unsigned v3 = *(const unsigned*)(Abase + (size_t)n3 * 2048 + coff);
        a0 += __uint_as_float(v0 << 16) + __uint_as_float(v1 << 16)
            + __uint_as_float(v2 << 16) + __uint_as_float(v3 << 16);
        a1 += __uint_as_float(v0 & 0xffff0000u) + __uint_as_float(v1 & 0xffff0000u)
            + __uint_as_float(v2 & 0xffff0000u) + __uint_as_float(v3 & 0xffff0000u);
    }
    for (; j < deg; ++j) {
        unsigned v0 = *(const unsigned*)(Abase + (size_t)al[j] * 2048 + coff);
        a0 += __uint_as_float(v0 << 16);
        a1 += __uint_as_float(v0 & 0xffff0000u);
    }
    float sc = 1.0f / fmaxf((float)deg, 1.0f);
    __hip_bfloat16 r0 = __float2bfloat16(a0 * sc);
    __hip_bfloat16 r1 = __float2bfloat16(a1 * sc);
    // agg chunk: A cols [q*128, q*128+128) -> byte offset q*256 + lane*4
    __hip_bfloat16* o = (__hip_bfloat16*)((char*)A + (size_t)node * 2048 + (size_t)q * 256 + lane * 4);
    o[0] = r0;
    o[1] = r1;
}

// ---------------- GEMM: out = relu(A @ W^T + b) + residual (FROZEN) ------------
__global__ __launch_bounds__(256) void gemm_kernel(const __hip_bfloat16* __restrict__ A,
                                                   const __hip_bfloat16* __restrict__ Wb,
                                                   const float* __restrict__ bias,
                                                   const float* __restrict__ resid,
                                                   float* __restrict__ out) {
    __shared__ __hip_bfloat16 As[2][64 * 32];
    __shared__ __hip_bfloat16 Bs[2][128 * 32];
    const int tid = threadIdx.x;
    const int lane = tid & 63;
    const int w = tid >> 6;
    const int wr = w >> 1, wc = w & 1;   // 2x2 waves, wave tile 32x64

    int bid = blockIdx.x;
    int tl = (bid & 7) * 79 + (bid >> 3);
    int mx = tl >> 2, ny = tl & 3;
    const size_t arow0 = (size_t)mx * 64;
    const size_t bcol0 = (size_t)ny * 128;

    f32x4 acc[2][4] = {};

    const int rsw = ((lane & 15) >> 1) & 3;
    const int csw = (((lane >> 4) ^ rsw) & 3) * 8;

#define STAGE(buf, t)                                                                \
    {                                                                                \
        int r = tid >> 2, sl = tid & 3;                                              \
        int c8 = sl ^ ((r >> 1) & 3);                                                \
        const __hip_bfloat16* ga = A + (size_t)(arow0 + r) * 1024 + (t) * 32 + c8 * 8; \
        __builtin_amdgcn_global_load_lds(                                            \
            (const __attribute__((address_space(1))) void*)ga,                       \
            (__attribute__((address_space(3))) void*)(As[buf] + tid * 8), 16, 0, 0); \
        _Pragma("unroll")                                                            \
        for (int it = 0; it < 2; ++it) {                                             \
            int j = tid + it * 256;                                                  \
            int rb = j >> 2, slb = j & 3;                                            \
            int cb8 = slb ^ ((rb >> 1) & 3);                                         \
            const __hip_bfloat16* gb = Wb + (size_t)(bcol0 + rb) * 1024 + (t) * 32 + cb8 * 8; \
            __builtin_amdgcn_global_load_lds(                                        \
                (const __attribute__((address_space(1))) void*)gb,                   \
                (__attribute__((address_space(3))) void*)(Bs[buf] + j * 8), 16, 0, 0); \
        }                                                                            \
    }

    STAGE(0, 0)
    __syncthreads();

    for (int t = 0; t < 32; ++t) {
        int p = t & 1;
        if (t + 1 < 32) STAGE(p ^ 1, t + 1)

        bf16x8 af[2], bfr[4];
        #pragma unroll
        for (int m = 0; m < 2; ++m)
            af[m] = *(const bf16x8*)(As[p] + (wr * 32 + m * 16 + (lane & 15)) * 32 + csw);
        #pragma unroll
        for (int n = 0; n < 4; ++n)
            bfr[n] = *(const bf16x8*)(Bs[p] + (wc * 64 + n * 16 + (lane & 15)) * 32 + csw);
        #pragma unroll
        for (int m = 0; m < 2; ++m)
            #pragma unroll
            for (int n = 0; n < 4; ++n)
                acc[m][n] = __builtin_amdgcn_mfma_f32_16x16x32_bf16(af[m], bfr[n], acc[m][n], 0, 0, 0);
        __syncthreads();
    }
#undef STAGE

    #pragma unroll
    for (int m = 0; m < 2; ++m) {
        int rowb = (int)arow0 + wr * 32 + m * 16 + (lane >> 4) * 4;
        #pragma unroll
        for (int n = 0; n < 4; ++n) {
            int col = (int)bcol0 + wc * 64 + n * 16 + (lane & 15);
            float bv = bias[col];
            #pragma unroll
            for (int j = 0; j < 4; ++j) {
                int row = rowb + j;
                if (row < N_NODES) {
                    float v = acc[m][n][j] + bv;
                    v = v > 0.0f ? v : 0.0f;
                    out[(size_t)row * 512 + col] = v + resid[(size_t)row * 512 + col];
                }
            }
        }
    }
}

extern "C" void kernel_launch(void* const* d_in, const int* in_sizes, int n_in,
                              void* d_out, int out_size, void* d_ws, size_t ws_size,
                              hipStream_t stream) {
    const float* node  = (const float*)d_in[0];
    const int*   eidx  = (const int*)d_in[1];
    const float* gamma = (const float*)d_in[2];
    const float* beta  = (const float*)d_in[3];
    const float* wl    = (const float*)d_in[4];
    const float* bl    = (const float*)d_in[5];
    const float* wr    = (const float*)d_in[6];
    float* out = (float*)d_out;
    const int E = in_sizes[1] / 2;

    char* ws = (char*)d_ws;
    int* cnt = (int*)ws;                                   // [10240]
    int* adj = cnt + 10240;                                // [N_NODES * DEGCAP]
    size_t adj_bytes = ((size_t)N_NODES * DEGCAP * 4 + 255) & ~(size_t)255;
    __hip_bfloat16* A = (__hip_bfloat16*)((char*)adj + adj_bytes);
    __hip_bfloat16* W = (__hip_bfloat16*)((char*)A + (size_t)MPAD * 1024 * 2);

    const int fill_start = 512 + 2500;
    const int nFill = (E + 255) / 256;

    zero_kernel<<<40, 256, 0, stream>>>(cnt);
    phase1_kernel<<<fill_start + nFill, 256, 0, stream>>>(
        wl, wr, W, node, gamma, beta, A, eidx, cnt, adj, E, fill_start);
    gather_kernel<<<10000, 256, 0, stream>>>(cnt, adj, A);
    gemm_kernel<<<632, 256, 0, stream>>>(A, W, bl, node, out);
}

// Round 8
// 71.847 us; speedup vs baseline: 1.1102x; 1.1102x over previous
//
#include <hip/hip_runtime.h>
#include <hip/hip_bf16.h>

typedef float f32x4 __attribute__((ext_vector_type(4)));
typedef __bf16 bf16x8 __attribute__((ext_vector_type(8)));
typedef unsigned short u16x8 __attribute__((ext_vector_type(8)));

#define N_NODES 10000
#define DIM 512
#define MPAD 10112   // 158 * 64
#define DEGCAP 96    // max degree bucket (Poisson(15): P(deg>=96) ~ 1e-40)

// ---------------- zero cnt ------------------------------------------------------
__global__ __launch_bounds__(256) void zero_kernel(int* __restrict__ cnt) {
    cnt[blockIdx.x * 256 + threadIdx.x] = 0;
}

// ====== phase1: packw | layernorm | bucket-fill adjacency (grid-partitioned) ===
__global__ __launch_bounds__(256) void phase1_kernel(
    const float* __restrict__ wl, const float* __restrict__ wr,
    __hip_bfloat16* __restrict__ W,
    const float* __restrict__ xin, const float* __restrict__ gamma,
    const float* __restrict__ beta, __hip_bfloat16* __restrict__ A,
    const int* __restrict__ eidx, int* __restrict__ cnt, int* __restrict__ adj,
    int E, int fill_start) {
    int b = blockIdx.x;
    int tid = threadIdx.x;

    if (b < 512) {
        // pack W = [w_l | w_r] rows -> bf16 [512][1024]
        int idx = b * 256 + tid;
        int base = idx * 4;
        int d = base >> 10;
        int k = base & 1023;
        const float* src = (k < 512) ? (wl + d * 512 + k) : (wr + d * 512 + (k - 512));
        float4 v = *(const float4*)src;
        __hip_bfloat16* o = W + (size_t)d * 1024 + k;
        o[0] = __float2bfloat16(v.x);
        o[1] = __float2bfloat16(v.y);
        o[2] = __float2bfloat16(v.z);
        o[3] = __float2bfloat16(v.w);
    } else if (b < fill_start) {
        // LayerNorm, one wave per row
        int row = (b - 512) * 4 + (tid >> 6);
        int lane = tid & 63;
        const float* xr = xin + (size_t)row * DIM + lane * 8;
        float4 v0 = *(const float4*)xr;
        float4 v1 = *(const float4*)(xr + 4);
        float s  = v0.x + v0.y + v0.z + v0.w + v1.x + v1.y + v1.z + v1.w;
        float ss = v0.x*v0.x + v0.y*v0.y + v0.z*v0.z + v0.w*v0.w
                 + v1.x*v1.x + v1.y*v1.y + v1.z*v1.z + v1.w*v1.w;
        #pragma unroll
        for (int o = 32; o > 0; o >>= 1) {
            s  += __shfl_xor(s, o, 64);
            ss += __shfl_xor(ss, o, 64);
        }
        float mu  = s * (1.0f / 512.0f);
        float var = ss * (1.0f / 512.0f) - mu * mu;
        float rstd = rsqrtf(var + 1e-5f);
        float4 g0 = *(const float4*)(gamma + lane * 8);
        float4 g1 = *(const float4*)(gamma + lane * 8 + 4);
        float4 b0 = *(const float4*)(beta + lane * 8);
        float4 b1 = *(const float4*)(beta + lane * 8 + 4);
        __hip_bfloat16* a = A + (size_t)row * 1024 + 512 + lane * 8;
        a[0] = __float2bfloat16((v0.x - mu) * rstd * g0.x + b0.x);
        a[1] = __float2bfloat16((v0.y - mu) * rstd * g0.y + b0.y);
        a[2] = __float2bfloat16((v0.z - mu) * rstd * g0.z + b0.z);
        a[3] = __float2bfloat16((v0.w - mu) * rstd * g0.w + b0.w);
        a[4] = __float2bfloat16((v1.x - mu) * rstd * g1.x + b1.x);
        a[5] = __float2bfloat16((v1.y - mu) * rstd * g1.y + b1.y);
        a[6] = __float2bfloat16((v1.z - mu) * rstd * g1.z + b1.z);
        a[7] = __float2bfloat16((v1.w - mu) * rstd * g1.w + b1.w);
    } else {
        // single-pass bucket fill: adj[dst*DEGCAP + pos] = src
        int i = (b - fill_start) * 256 + tid;
        if (i < E) {
            int dst = eidx[E + i];
            int src = eidx[i];
            int pos = atomicAdd(&cnt[dst], 1);
            if (pos < DEGCAP) adj[dst * DEGCAP + pos] = src;
        }
    }
}

// ---------------- gather: wave/node, 8-deep MLP unroll -------------------------
__global__ __launch_bounds__(256) void gather_kernel(const int* __restrict__ cnt,
                                                     const int* __restrict__ adj,
                                                     __hip_bfloat16* __restrict__ A) {
    int gw = (blockIdx.x * 256 + threadIdx.x) >> 6;
    int lane = threadIdx.x & 63;
    int deg = cnt[gw];
    const int* al = adj + gw * DEGCAP;
    float acc0[8] = {}, acc1[8] = {};
    int j = 0;
    for (; j + 8 <= deg; j += 8) {
        int a0 = al[j], a1 = al[j+1], a2 = al[j+2], a3 = al[j+3];
        int a4 = al[j+4], a5 = al[j+5], a6 = al[j+6], a7 = al[j+7];
        u16x8 v0 = *(const u16x8*)(A + (size_t)a0 * 1024 + 512 + lane * 8);
        u16x8 v1 = *(const u16x8*)(A + (size_t)a1 * 1024 + 512 + lane * 8);
        u16x8 v2 = *(const u16x8*)(A + (size_t)a2 * 1024 + 512 + lane * 8);
        u16x8 v3 = *(const u16x8*)(A + (size_t)a3 * 1024 + 512 + lane * 8);
        u16x8 v4 = *(const u16x8*)(A + (size_t)a4 * 1024 + 512 + lane * 8);
        u16x8 v5 = *(const u16x8*)(A + (size_t)a5 * 1024 + 512 + lane * 8);
        u16x8 v6 = *(const u16x8*)(A + (size_t)a6 * 1024 + 512 + lane * 8);
        u16x8 v7 = *(const u16x8*)(A + (size_t)a7 * 1024 + 512 + lane * 8);
        #pragma unroll
        for (int k = 0; k < 8; ++k) {
            acc0[k] += __uint_as_float((unsigned)v0[k] << 16)
                     + __uint_as_float((unsigned)v1[k] << 16)
                     + __uint_as_float((unsigned)v2[k] << 16)
                     + __uint_as_float((unsigned)v3[k] << 16);
            acc1[k] += __uint_as_float((unsigned)v4[k] << 16)
                     + __uint_as_float((unsigned)v5[k] << 16)
                     + __uint_as_float((unsigned)v6[k] << 16)
                     + __uint_as_float((unsigned)v7[k] << 16);
        }
    }
    for (; j + 4 <= deg; j += 4) {
        int a0 = al[j], a1 = al[j+1], a2 = al[j+2], a3 = al[j+3];
        u16x8 v0 = *(const u16x8*)(A + (size_t)a0 * 1024 + 512 + lane * 8);
        u16x8 v1 = *(const u16x8*)(A + (size_t)a1 * 1024 + 512 + lane * 8);
        u16x8 v2 = *(const u16x8*)(A + (size_t)a2 * 1024 + 512 + lane * 8);
        u16x8 v3 = *(const u16x8*)(A + (size_t)a3 * 1024 + 512 + lane * 8);
        #pragma unroll
        for (int k = 0; k < 8; ++k) {
            acc0[k] += __uint_as_float((unsigned)v0[k] << 16)
                     + __uint_as_float((unsigned)v1[k] << 16);
            acc1[k] += __uint_as_float((unsigned)v2[k] << 16)
                     + __uint_as_float((unsigned)v3[k] << 16);
        }
    }
    for (; j < deg; ++j) {
        int a0 = al[j];
        u16x8 v0 = *(const u16x8*)(A + (size_t)a0 * 1024 + 512 + lane * 8);
        #pragma unroll
        for (int k = 0; k < 8; ++k)
            acc0[k] += __uint_as_float((unsigned)v0[k] << 16);
    }
    float sc = 1.0f / fmaxf((float)deg, 1.0f);
    __hip_bfloat16* o = A + (size_t)gw * 1024 + lane * 8;
    #pragma unroll
    for (int k = 0; k < 8; ++k)
        o[k] = __float2bfloat16((acc0[k] + acc1[k]) * sc);
}

// ---------------- GEMM: out = relu(A @ W^T + b) + residual ---------------------
// BM=64, BN=64, BK=32. Grid 158*8 = 1264 = 8*158 (XCD-chunked swizzle):
// ~5 blocks/CU (was 2.5) to hide the per-iter barrier drain.
__global__ __launch_bounds__(256) void gemm_kernel(const __hip_bfloat16* __restrict__ A,
                                                   const __hip_bfloat16* __restrict__ Wb,
                                                   const float* __restrict__ bias,
                                                   const float* __restrict__ resid,
                                                   float* __restrict__ out) {
    __shared__ __hip_bfloat16 As[2][64 * 32];
    __shared__ __hip_bfloat16 Bs[2][64 * 32];
    const int tid = threadIdx.x;
    const int lane = tid & 63;
    const int w = tid >> 6;
    const int wr = w >> 1, wc = w & 1;   // 2x2 waves, wave tile 32x32

    int bid = blockIdx.x;
    int tl = (bid & 7) * 158 + (bid >> 3);   // XCD-chunked bijective swizzle
    int mx = tl >> 3, ny = tl & 7;           // 8 consecutive tl share the A-panel
    const size_t arow0 = (size_t)mx * 64;
    const size_t bcol0 = (size_t)ny * 64;

    f32x4 acc[2][2] = {};

    const int rsw = ((lane & 15) >> 1) & 3;
    const int csw = (((lane >> 4) ^ rsw) & 3) * 8;

#define STAGE(buf, t)                                                                \
    {                                                                                \
        int r = tid >> 2, sl = tid & 3;                                              \
        int c8 = sl ^ ((r >> 1) & 3);                                                \
        const __hip_bfloat16* ga = A + (size_t)(arow0 + r) * 1024 + (t) * 32 + c8 * 8; \
        __builtin_amdgcn_global_load_lds(                                            \
            (const __attribute__((address_space(1))) void*)ga,                       \
            (__attribute__((address_space(3))) void*)(As[buf] + tid * 8), 16, 0, 0); \
        const __hip_bfloat16* gb = Wb + (size_t)(bcol0 + r) * 1024 + (t) * 32 + c8 * 8; \
        __builtin_amdgcn_global_load_lds(                                            \
            (const __attribute__((address_space(1))) void*)gb,                       \
            (__attribute__((address_space(3))) void*)(Bs[buf] + tid * 8), 16, 0, 0); \
    }

    STAGE(0, 0)
    __syncthreads();

    for (int t = 0; t < 32; ++t) {
        int p = t & 1;
        if (t + 1 < 32) STAGE(p ^ 1, t + 1)

        bf16x8 af[2], bfr[2];
        #pragma unroll
        for (int m = 0; m < 2; ++m)
            af[m] = *(const bf16x8*)(As[p] + (wr * 32 + m * 16 + (lane & 15)) * 32 + csw);
        #pragma unroll
        for (int n = 0; n < 2; ++n)
            bfr[n] = *(const bf16x8*)(Bs[p] + (wc * 32 + n * 16 + (lane & 15)) * 32 + csw);
        #pragma unroll
        for (int m = 0; m < 2; ++m)
            #pragma unroll
            for (int n = 0; n < 2; ++n)
                acc[m][n] = __builtin_amdgcn_mfma_f32_16x16x32_bf16(af[m], bfr[n], acc[m][n], 0, 0, 0);
        __syncthreads();
    }
#undef STAGE

    #pragma unroll
    for (int m = 0; m < 2; ++m) {
        int rowb = (int)arow0 + wr * 32 + m * 16 + (lane >> 4) * 4;
        #pragma unroll
        for (int n = 0; n < 2; ++n) {
            int col = (int)bcol0 + wc * 32 + n * 16 + (lane & 15);
            float bv = bias[col];
            #pragma unroll
            for (int j = 0; j < 4; ++j) {
                int row = rowb + j;
                if (row < N_NODES) {
                    float v = acc[m][n][j] + bv;
                    v = v > 0.0f ? v : 0.0f;
                    out[(size_t)row * 512 + col] = v + resid[(size_t)row * 512 + col];
                }
            }
        }
    }
}

extern "C" void kernel_launch(void* const* d_in, const int* in_sizes, int n_in,
                              void* d_out, int out_size, void* d_ws, size_t ws_size,
                              hipStream_t stream) {
    const float* node  = (const float*)d_in[0];
    const int*   eidx  = (const int*)d_in[1];
    const float* gamma = (const float*)d_in[2];
    const float* beta  = (const float*)d_in[3];
    const float* wl    = (const float*)d_in[4];
    const float* bl    = (const float*)d_in[5];
    const float* wr    = (const float*)d_in[6];
    float* out = (float*)d_out;
    const int E = in_sizes[1] / 2;

    char* ws = (char*)d_ws;
    int* cnt = (int*)ws;                                   // [10240]
    int* adj = cnt + 10240;                                // [N_NODES * DEGCAP]
    size_t adj_bytes = ((size_t)N_NODES * DEGCAP * 4 + 255) & ~(size_t)255;
    __hip_bfloat16* A = (__hip_bfloat16*)((char*)adj + adj_bytes);
    __hip_bfloat16* W = (__hip_bfloat16*)((char*)A + (size_t)MPAD * 1024 * 2);

    const int fill_start = 512 + 2500;
    const int nFill = (E + 255) / 256;

    zero_kernel<<<40, 256, 0, stream>>>(cnt);
    phase1_kernel<<<fill_start + nFill, 256, 0, stream>>>(
        wl, wr, W, node, gamma, beta, A, eidx, cnt, adj, E, fill_start);
    gather_kernel<<<(N_NODES * 64) / 256, 256, 0, stream>>>(cnt, adj, A);
    gemm_kernel<<<1264, 256, 0, stream>>>(A, W, bl, node, out);
}

// Round 9
// 70.160 us; speedup vs baseline: 1.1369x; 1.0241x over previous
//
#include <hip/hip_runtime.h>
#include <hip/hip_bf16.h>

typedef float f32x4 __attribute__((ext_vector_type(4)));
typedef __bf16 bf16x8 __attribute__((ext_vector_type(8)));
typedef unsigned short u16x8 __attribute__((ext_vector_type(8)));

#define N_NODES 10000
#define DIM 512
#define MPAD 10112   // 158 * 64
#define DEGCAP 96    // max degree bucket (Poisson(15): P(deg>=96) ~ 1e-40)

// ---------------- zero cnt ------------------------------------------------------
__global__ __launch_bounds__(256) void zero_kernel(int* __restrict__ cnt) {
    cnt[blockIdx.x * 256 + threadIdx.x] = 0;
}

// ====== phase1: packw | layernorm | bucket-fill adjacency (grid-partitioned) ===
__global__ __launch_bounds__(256) void phase1_kernel(
    const float* __restrict__ wl, const float* __restrict__ wr,
    __hip_bfloat16* __restrict__ W,
    const float* __restrict__ xin, const float* __restrict__ gamma,
    const float* __restrict__ beta, __hip_bfloat16* __restrict__ A,
    const int* __restrict__ eidx, int* __restrict__ cnt, int* __restrict__ adj,
    int E, int fill_start) {
    int b = blockIdx.x;
    int tid = threadIdx.x;

    if (b < 512) {
        // pack W = [w_l | w_r] rows -> bf16 [512][1024]
        int idx = b * 256 + tid;
        int base = idx * 4;
        int d = base >> 10;
        int k = base & 1023;
        const float* src = (k < 512) ? (wl + d * 512 + k) : (wr + d * 512 + (k - 512));
        float4 v = *(const float4*)src;
        __hip_bfloat16* o = W + (size_t)d * 1024 + k;
        o[0] = __float2bfloat16(v.x);
        o[1] = __float2bfloat16(v.y);
        o[2] = __float2bfloat16(v.z);
        o[3] = __float2bfloat16(v.w);
    } else if (b < fill_start) {
        // LayerNorm, one wave per row
        int row = (b - 512) * 4 + (tid >> 6);
        int lane = tid & 63;
        const float* xr = xin + (size_t)row * DIM + lane * 8;
        float4 v0 = *(const float4*)xr;
        float4 v1 = *(const float4*)(xr + 4);
        float s  = v0.x + v0.y + v0.z + v0.w + v1.x + v1.y + v1.z + v1.w;
        float ss = v0.x*v0.x + v0.y*v0.y + v0.z*v0.z + v0.w*v0.w
                 + v1.x*v1.x + v1.y*v1.y + v1.z*v1.z + v1.w*v1.w;
        #pragma unroll
        for (int o = 32; o > 0; o >>= 1) {
            s  += __shfl_xor(s, o, 64);
            ss += __shfl_xor(ss, o, 64);
        }
        float mu  = s * (1.0f / 512.0f);
        float var = ss * (1.0f / 512.0f) - mu * mu;
        float rstd = rsqrtf(var + 1e-5f);
        float4 g0 = *(const float4*)(gamma + lane * 8);
        float4 g1 = *(const float4*)(gamma + lane * 8 + 4);
        float4 b0 = *(const float4*)(beta + lane * 8);
        float4 b1 = *(const float4*)(beta + lane * 8 + 4);
        __hip_bfloat16* a = A + (size_t)row * 1024 + 512 + lane * 8;
        a[0] = __float2bfloat16((v0.x - mu) * rstd * g0.x + b0.x);
        a[1] = __float2bfloat16((v0.y - mu) * rstd * g0.y + b0.y);
        a[2] = __float2bfloat16((v0.z - mu) * rstd * g0.z + b0.z);
        a[3] = __float2bfloat16((v0.w - mu) * rstd * g0.w + b0.w);
        a[4] = __float2bfloat16((v1.x - mu) * rstd * g1.x + b1.x);
        a[5] = __float2bfloat16((v1.y - mu) * rstd * g1.y + b1.y);
        a[6] = __float2bfloat16((v1.z - mu) * rstd * g1.z + b1.z);
        a[7] = __float2bfloat16((v1.w - mu) * rstd * g1.w + b1.w);
    } else {
        // single-pass bucket fill: adj[dst*DEGCAP + pos] = src
        int i = (b - fill_start) * 256 + tid;
        if (i < E) {
            int dst = eidx[E + i];
            int src = eidx[i];
            int pos = atomicAdd(&cnt[dst], 1);
            if (pos < DEGCAP) adj[dst * DEGCAP + pos] = src;
        }
    }
}

// ---------------- gather: wave/node, 8-deep MLP unroll (FROZEN) ----------------
__global__ __launch_bounds__(256) void gather_kernel(const int* __restrict__ cnt,
                                                     const int* __restrict__ adj,
                                                     __hip_bfloat16* __restrict__ A) {
    int gw = (blockIdx.x * 256 + threadIdx.x) >> 6;
    int lane = threadIdx.x & 63;
    int deg = cnt[gw];
    const int* al = adj + gw * DEGCAP;
    float acc0[8] = {}, acc1[8] = {};
    int j = 0;
    for (; j + 8 <= deg; j += 8) {
        int a0 = al[j], a1 = al[j+1], a2 = al[j+2], a3 = al[j+3];
        int a4 = al[j+4], a5 = al[j+5], a6 = al[j+6], a7 = al[j+7];
        u16x8 v0 = *(const u16x8*)(A + (size_t)a0 * 1024 + 512 + lane * 8);
        u16x8 v1 = *(const u16x8*)(A + (size_t)a1 * 1024 + 512 + lane * 8);
        u16x8 v2 = *(const u16x8*)(A + (size_t)a2 * 1024 + 512 + lane * 8);
        u16x8 v3 = *(const u16x8*)(A + (size_t)a3 * 1024 + 512 + lane * 8);
        u16x8 v4 = *(const u16x8*)(A + (size_t)a4 * 1024 + 512 + lane * 8);
        u16x8 v5 = *(const u16x8*)(A + (size_t)a5 * 1024 + 512 + lane * 8);
        u16x8 v6 = *(const u16x8*)(A + (size_t)a6 * 1024 + 512 + lane * 8);
        u16x8 v7 = *(const u16x8*)(A + (size_t)a7 * 1024 + 512 + lane * 8);
        #pragma unroll
        for (int k = 0; k < 8; ++k) {
            acc0[k] += __uint_as_float((unsigned)v0[k] << 16)
                     + __uint_as_float((unsigned)v1[k] << 16)
                     + __uint_as_float((unsigned)v2[k] << 16)
                     + __uint_as_float((unsigned)v3[k] << 16);
            acc1[k] += __uint_as_float((unsigned)v4[k] << 16)
                     + __uint_as_float((unsigned)v5[k] << 16)
                     + __uint_as_float((unsigned)v6[k] << 16)
                     + __uint_as_float((unsigned)v7[k] << 16);
        }
    }
    for (; j + 4 <= deg; j += 4) {
        int a0 = al[j], a1 = al[j+1], a2 = al[j+2], a3 = al[j+3];
        u16x8 v0 = *(const u16x8*)(A + (size_t)a0 * 1024 + 512 + lane * 8);
        u16x8 v1 = *(const u16x8*)(A + (size_t)a1 * 1024 + 512 + lane * 8);
        u16x8 v2 = *(const u16x8*)(A + (size_t)a2 * 1024 + 512 + lane * 8);
        u16x8 v3 = *(const u16x8*)(A + (size_t)a3 * 1024 + 512 + lane * 8);
        #pragma unroll
        for (int k = 0; k < 8; ++k) {
            acc0[k] += __uint_as_float((unsigned)v0[k] << 16)
                     + __uint_as_float((unsigned)v1[k] << 16);
            acc1[k] += __uint_as_float((unsigned)v2[k] << 16)
                     + __uint_as_float((unsigned)v3[k] << 16);
        }
    }
    for (; j < deg; ++j) {
        int a0 = al[j];
        u16x8 v0 = *(const u16x8*)(A + (size_t)a0 * 1024 + 512 + lane * 8);
        #pragma unroll
        for (int k = 0; k < 8; ++k)
            acc0[k] += __uint_as_float((unsigned)v0[k] << 16);
    }
    float sc = 1.0f / fmaxf((float)deg, 1.0f);
    __hip_bfloat16* o = A + (size_t)gw * 1024 + lane * 8;
    #pragma unroll
    for (int k = 0; k < 8; ++k)
        o[k] = __float2bfloat16((acc0[k] + acc1[k]) * sc);
}

// ---------------- GEMM: out = relu(A @ W^T + b) + residual ---------------------
// BM=64, BN=64, BK=32. Grid 1264 = 8*158 (XCD-chunked swizzle).
// 3-buffer LDS pipeline, depth-2 prefetch, counted vmcnt (never 0 in loop):
// tile t+2's DMA targets buf (t-1)%3 whose reads were lgkm-consumed before
// the iter-t barrier -> no race. vmcnt(2) BEFORE barrier => all waves' tile-t
// loads landed when any wave proceeds.
__global__ __launch_bounds__(256) void gemm_kernel(const __hip_bfloat16* __restrict__ A,
                                                   const __hip_bfloat16* __restrict__ Wb,
                                                   const float* __restrict__ bias,
                                                   const float* __restrict__ resid,
                                                   float* __restrict__ out) {
    __shared__ __hip_bfloat16 As[3][64 * 32];
    __shared__ __hip_bfloat16 Bs[3][64 * 32];
    const int tid = threadIdx.x;
    const int lane = tid & 63;
    const int w = tid >> 6;
    const int wr = w >> 1, wc = w & 1;   // 2x2 waves, wave tile 32x32

    int bid = blockIdx.x;
    int tl = (bid & 7) * 158 + (bid >> 3);   // XCD-chunked bijective swizzle
    int mx = tl >> 3, ny = tl & 7;           // 8 consecutive tl share the A-panel
    const size_t arow0 = (size_t)mx * 64;
    const size_t bcol0 = (size_t)ny * 64;

    f32x4 acc[2][2] = {};

    const int rsw = ((lane & 15) >> 1) & 3;
    const int csw = (((lane >> 4) ^ rsw) & 3) * 8;

#define STAGE(buf, t)                                                                \
    {                                                                                \
        int r = tid >> 2, sl = tid & 3;                                              \
        int c8 = sl ^ ((r >> 1) & 3);                                                \
        const __hip_bfloat16* ga = A + (size_t)(arow0 + r) * 1024 + (t) * 32 + c8 * 8; \
        __builtin_amdgcn_global_load_lds(                                            \
            (const __attribute__((address_space(1))) void*)ga,                       \
            (__attribute__((address_space(3))) void*)(As[buf] + tid * 8), 16, 0, 0); \
        const __hip_bfloat16* gb = Wb + (size_t)(bcol0 + r) * 1024 + (t) * 32 + c8 * 8; \
        __builtin_amdgcn_global_load_lds(                                            \
            (const __attribute__((address_space(1))) void*)gb,                       \
            (__attribute__((address_space(3))) void*)(Bs[buf] + tid * 8), 16, 0, 0); \
    }

    STAGE(0, 0)
    STAGE(1, 1)

    #pragma unroll
    for (int t = 0; t < 32; ++t) {
        if (t < 31) { asm volatile("s_waitcnt vmcnt(2)" ::: "memory"); }
        else        { asm volatile("s_waitcnt vmcnt(0)" ::: "memory"); }
        __builtin_amdgcn_s_barrier();
        __builtin_amdgcn_sched_barrier(0);
        if (t + 2 < 32) STAGE((t + 2) % 3, t + 2)

        const int p = t % 3;
        bf16x8 af[2], bfr[2];
        #pragma unroll
        for (int m = 0; m < 2; ++m)
            af[m] = *(const bf16x8*)(As[p] + (wr * 32 + m * 16 + (lane & 15)) * 32 + csw);
        #pragma unroll
        for (int n = 0; n < 2; ++n)
            bfr[n] = *(const bf16x8*)(Bs[p] + (wc * 32 + n * 16 + (lane & 15)) * 32 + csw);
        #pragma unroll
        for (int m = 0; m < 2; ++m)
            #pragma unroll
            for (int n = 0; n < 2; ++n)
                acc[m][n] = __builtin_amdgcn_mfma_f32_16x16x32_bf16(af[m], bfr[n], acc[m][n], 0, 0, 0);
    }
#undef STAGE

    #pragma unroll
    for (int m = 0; m < 2; ++m) {
        int rowb = (int)arow0 + wr * 32 + m * 16 + (lane >> 4) * 4;
        #pragma unroll
        for (int n = 0; n < 2; ++n) {
            int col = (int)bcol0 + wc * 32 + n * 16 + (lane & 15);
            float bv = bias[col];
            #pragma unroll
            for (int j = 0; j < 4; ++j) {
                int row = rowb + j;
                if (row < N_NODES) {
                    float v = acc[m][n][j] + bv;
                    v = v > 0.0f ? v : 0.0f;
                    out[(size_t)row * 512 + col] = v + resid[(size_t)row * 512 + col];
                }
            }
        }
    }
}

extern "C" void kernel_launch(void* const* d_in, const int* in_sizes, int n_in,
                              void* d_out, int out_size, void* d_ws, size_t ws_size,
                              hipStream_t stream) {
    const float* node  = (const float*)d_in[0];
    const int*   eidx  = (const int*)d_in[1];
    const float* gamma = (const float*)d_in[2];
    const float* beta  = (const float*)d_in[3];
    const float* wl    = (const float*)d_in[4];
    const float* bl    = (const float*)d_in[5];
    const float* wr    = (const float*)d_in[6];
    float* out = (float*)d_out;
    const int E = in_sizes[1] / 2;

    char* ws = (char*)d_ws;
    int* cnt = (int*)ws;                                   // [10240]
    int* adj = cnt + 10240;                                // [N_NODES * DEGCAP]
    size_t adj_bytes = ((size_t)N_NODES * DEGCAP * 4 + 255) & ~(size_t)255;
    __hip_bfloat16* A = (__hip_bfloat16*)((char*)adj + adj_bytes);
    __hip_bfloat16* W = (__hip_bfloat16*)((char*)A + (size_t)MPAD * 1024 * 2);

    const int fill_start = 512 + 2500;
    const int nFill = (E + 255) / 256;

    zero_kernel<<<40, 256, 0, stream>>>(cnt);
    phase1_kernel<<<fill_start + nFill, 256, 0, stream>>>(
        wl, wr, W, node, gamma, beta, A, eidx, cnt, adj, E, fill_start);
    gather_kernel<<<(N_NODES * 64) / 256, 256, 0, stream>>>(cnt, adj, A);
    gemm_kernel<<<1264, 256, 0, stream>>>(A, W, bl, node, out);
}